// Round 1
// baseline (3261.898 us; speedup 1.0000x reference)
//
#include <hip/hip_runtime.h>
#include <cstdint>
#include <cstddef>

// Problem constants (fixed by the reference)
constexpr int cB = 2, cS = 1024, cD = 512, cH = 8, cDK = 64, cDFF = 2048;
constexpr int cBS = cB * cS;
constexpr float kNEG = -1e19f;

// ============================ GEMM ============================
// C[M,N] = act(A op B + bias) + resid, batched over z=(g1,g2).
// TA: A stored [K,M] (A[k*lda+m]); TB: B stored [N,K] (B[n*ldb+k]).
// M,N multiples of 64; K multiple of 16 (true for every call here).
template<bool TA, bool TB, bool GELU_ACT>
__global__ __launch_bounds__(256) void gemm_kernel(
    const float* __restrict__ A, const float* __restrict__ Bm, float* __restrict__ C,
    const float* __restrict__ bias, const float* __restrict__ resid,
    int K, int lda, int ldb, int ldc,
    long long a1, long long a2, long long b1, long long b2,
    long long c1, long long c2, int G2)
{
    __shared__ float As[16][65];
    __shared__ float Bs[16][65];
    const int z  = blockIdx.z;
    const int g1 = z / G2, g2 = z - g1 * G2;
    A  += (long long)g1 * a1 + (long long)g2 * a2;
    Bm += (long long)g1 * b1 + (long long)g2 * b2;
    const long long coff = (long long)g1 * c1 + (long long)g2 * c2;
    const int m0 = blockIdx.y << 6, n0 = blockIdx.x << 6;
    const int tid = threadIdx.x;
    const int tx = tid & 15, ty = tid >> 4;
    float acc[4][4] = {};
    for (int k0 = 0; k0 < K; k0 += 16) {
        if (!TA) {
            const int kk = tid & 15, mm = tid >> 4;
            #pragma unroll
            for (int it = 0; it < 4; ++it)
                As[kk][mm + 16 * it] = A[(long long)(m0 + mm + 16 * it) * lda + (k0 + kk)];
        } else {
            const int mm = tid & 63, kk = tid >> 6;
            #pragma unroll
            for (int it = 0; it < 4; ++it)
                As[kk + 4 * it][mm] = A[(long long)(k0 + kk + 4 * it) * lda + (m0 + mm)];
        }
        if (!TB) {
            const int nn = tid & 63, kk = tid >> 6;
            #pragma unroll
            for (int it = 0; it < 4; ++it)
                Bs[kk + 4 * it][nn] = Bm[(long long)(k0 + kk + 4 * it) * ldb + (n0 + nn)];
        } else {
            const int kk = tid & 15, nn = tid >> 4;
            #pragma unroll
            for (int it = 0; it < 4; ++it)
                Bs[kk][nn + 16 * it] = Bm[(long long)(n0 + nn + 16 * it) * ldb + (k0 + kk)];
        }
        __syncthreads();
        #pragma unroll
        for (int kk = 0; kk < 16; ++kk) {
            float a[4], b[4];
            #pragma unroll
            for (int i = 0; i < 4; ++i) a[i] = As[kk][ty + 16 * i];
            #pragma unroll
            for (int j = 0; j < 4; ++j) b[j] = Bs[kk][tx + 16 * j];
            #pragma unroll
            for (int i = 0; i < 4; ++i)
                #pragma unroll
                for (int j = 0; j < 4; ++j)
                    acc[i][j] = fmaf(a[i], b[j], acc[i][j]);
        }
        __syncthreads();
    }
    #pragma unroll
    for (int i = 0; i < 4; ++i) {
        const int row = m0 + ty + 16 * i;
        #pragma unroll
        for (int j = 0; j < 4; ++j) {
            const int col = n0 + tx + 16 * j;
            float v = acc[i][j];
            if (bias) v += bias[col];
            if (GELU_ACT) v = 0.5f * v * (1.0f + erff(v * 0.70710678118654752440f));
            const long long idx = coff + (long long)row * ldc + col;
            if (resid) v += resid[idx];
            C[idx] = v;
        }
    }
}

enum GemmMode { GM_NN = 0, GM_NT = 1, GM_TN = 2 };

static void gemm(hipStream_t st, GemmMode mode, bool gelu,
                 const float* A, const float* B, float* C,
                 const float* bias, const float* resid,
                 int M, int N, int K, int lda, int ldb, int ldc,
                 long long a1, long long a2, long long b1, long long b2,
                 long long c1, long long c2, int G1, int G2)
{
    dim3 grid(N / 64, M / 64, G1 * G2), blk(256);
    if (mode == GM_NN) {
        if (gelu)
            gemm_kernel<false, false, true><<<grid, blk, 0, st>>>(A, B, C, bias, resid, K, lda, ldb, ldc, a1, a2, b1, b2, c1, c2, G2);
        else
            gemm_kernel<false, false, false><<<grid, blk, 0, st>>>(A, B, C, bias, resid, K, lda, ldb, ldc, a1, a2, b1, b2, c1, c2, G2);
    } else if (mode == GM_NT) {
        gemm_kernel<false, true, false><<<grid, blk, 0, st>>>(A, B, C, bias, resid, K, lda, ldb, ldc, a1, a2, b1, b2, c1, c2, G2);
    } else {
        gemm_kernel<true, false, false><<<grid, blk, 0, st>>>(A, B, C, bias, resid, K, lda, ldb, ldc, a1, a2, b1, b2, c1, c2, G2);
    }
}

// ============================ softmax over QUERY dim ============================
// scoresT layout [B,H,S(k),S(q)] -> softmax over contiguous last dim q.
// CAUSAL: out = softmax(x + mask) * scale; else out = softmax((x + mask) * scale).
template<bool CAUSAL>
__global__ __launch_bounds__(256) void softmax_kernel(
    float* __restrict__ sc, const unsigned char* __restrict__ padq,
    const unsigned char* __restrict__ padk, float scale)
{
    const int r = blockIdx.x;             // (b*H + h)*S + k
    const int k = r & (cS - 1);
    const int b = r / (cH * cS);
    float* row = sc + (long long)r * cS;
    const bool pk = padk[b * cS + k] != 0;
    const int tid = threadIdx.x;
    float4 v4 = reinterpret_cast<const float4*>(row)[tid];
    float vals[4] = {v4.x, v4.y, v4.z, v4.w};
    #pragma unroll
    for (int u = 0; u < 4; ++u) {
        const int q = tid * 4 + u;
        bool masked = pk || (padq[b * cS + q] != 0);
        if (CAUSAL) masked = masked || (q < k);   // tril==0 where key index > query index
        float x = vals[u];
        if (masked) x += kNEG;
        if (!CAUSAL) x *= scale;
        vals[u] = x;
    }
    float m = fmaxf(fmaxf(vals[0], vals[1]), fmaxf(vals[2], vals[3]));
    #pragma unroll
    for (int off = 32; off > 0; off >>= 1) m = fmaxf(m, __shfl_down(m, off));
    __shared__ float red[8];
    if ((tid & 63) == 0) red[tid >> 6] = m;
    __syncthreads();
    const float rm = fmaxf(fmaxf(red[0], red[1]), fmaxf(red[2], red[3]));
    float e[4], s = 0.f;
    #pragma unroll
    for (int u = 0; u < 4; ++u) { e[u] = expf(vals[u] - rm); s += e[u]; }
    #pragma unroll
    for (int off = 32; off > 0; off >>= 1) s += __shfl_down(s, off);
    if ((tid & 63) == 0) red[4 + (tid >> 6)] = s;
    __syncthreads();
    float inv = 1.0f / (red[4] + red[5] + red[6] + red[7]);
    if (CAUSAL) inv *= scale;                 // scale AFTER softmax (original bug)
    v4.x = e[0] * inv; v4.y = e[1] * inv; v4.z = e[2] * inv; v4.w = e[3] * inv;
    reinterpret_cast<float4*>(row)[tid] = v4;
}

// ============================ batch-dim layer norm (B=2 closed form) ============================
__global__ __launch_bounds__(256) void ln_kernel(const float* __restrict__ x, float* __restrict__ out)
{
    const long long idx = (long long)blockIdx.x * 256 + threadIdx.x;   // over S*D
    const float x0 = x[idx], x1 = x[idx + (long long)cS * cD];
    const float diff = x0 - x1;
    const float stdv = fabsf(diff) * 0.70710678118654752440f;          // unbiased std, B=2
    const float o = (0.5f * diff) / (stdv + 1e-4f);
    out[idx] = o;
    out[idx + (long long)cS * cD] = -o;
}

// ============================ padding masks ============================
__global__ __launch_bounds__(256) void pad_in_kernel(const float* __restrict__ X, unsigned char* __restrict__ pad)
{
    const int r = blockIdx.x;                  // b*S + s
    const float* row = X + (long long)r * cD;
    const int tid = threadIdx.x;
    const bool nz = (row[tid] != 0.f) | (row[tid + 256] != 0.f);
    unsigned long long w = __ballot(nz);
    __shared__ unsigned long long sh[4];
    if ((tid & 63) == 0) sh[tid >> 6] = w;
    __syncthreads();
    if (tid == 0) pad[r] = ((sh[0] | sh[1] | sh[2] | sh[3]) == 0ULL) ? 1 : 0;
}

__global__ __launch_bounds__(256) void pad_dec_kernel(const float* __restrict__ outp, unsigned char* __restrict__ pad)
{
    const int r = blockIdx.x;                  // b*S + s
    const int s = r & (cS - 1);
    const int b = r >> 10;
    if (s == 0) { if (threadIdx.x == 0) pad[r] = 0; return; }   // prepended ones row: never pad
    const float* row = outp + ((long long)b * (cS - 1) + (s - 1)) * cD;
    const int tid = threadIdx.x;
    const bool nz = (row[tid] != 0.f) | (row[tid + 256] != 0.f);
    unsigned long long w = __ballot(nz);
    __shared__ unsigned long long sh[4];
    if ((tid & 63) == 0) sh[tid >> 6] = w;
    __syncthreads();
    if (tid == 0) pad[r] = ((sh[0] | sh[1] | sh[2] | sh[3]) == 0ULL) ? 1 : 0;
}

// ============================ positional encoding ============================
__device__ __forceinline__ float pe_val(int s, int d)
{
    const int i2 = d & ~1;
    const float dv = powf(10000.0f, -(float)i2 / (float)cD);
    const float ang = (float)s * dv;
    return (d & 1) ? cosf(ang) : sinf(ang);
}

__global__ __launch_bounds__(256) void posenc_enc_kernel(const float* __restrict__ X, float* __restrict__ out)
{
    const int r = blockIdx.x;                  // b*S + s
    const int s = r & (cS - 1);
    const int tid = threadIdx.x;
    #pragma unroll
    for (int u = 0; u < 2; ++u) {
        const int d = tid + 256 * u;
        out[(long long)r * cD + d] = X[(long long)r * cD + d] + pe_val(s, d);
    }
}

__global__ __launch_bounds__(256) void posenc_dec_kernel(const float* __restrict__ outp, float* __restrict__ out)
{
    const int r = blockIdx.x;                  // b*S + s
    const int s = r & (cS - 1);
    const int b = r >> 10;
    const int tid = threadIdx.x;
    #pragma unroll
    for (int u = 0; u < 2; ++u) {
        const int d = tid + 256 * u;
        const float base = (s == 0) ? 1.0f : outp[((long long)b * (cS - 1) + (s - 1)) * cD + d];
        out[(long long)r * cD + d] = base + pe_val(s, d);
    }
}

// ============================ final masked slice ============================
__global__ __launch_bounds__(256) void final_kernel(const float* __restrict__ cur,
                                                    const unsigned char* __restrict__ pad,
                                                    float* __restrict__ out)
{
    const int r = blockIdx.x;                  // b*(S-1) + (s-1)
    const int b = r / (cS - 1);
    const int s = r - b * (cS - 1) + 1;
    const int tid = threadIdx.x;
    const bool p = pad[b * cS + s] != 0;
    #pragma unroll
    for (int u = 0; u < 2; ++u) {
        const int d = tid + 256 * u;
        out[(long long)r * cD + d] = p ? 0.0f : cur[((long long)b * cS + s) * cD + d];
    }
}

// ============================ host orchestration ============================
struct Ws {
    float *t0, *t1, *t2, *t3, *att, *Q, *K, *V, *wc, *ffn, *sc;
    unsigned char *pin, *pout;
};

static void run_mha(hipStream_t st, const Ws& w,
                    const float* xq, const float* xkv,
                    const float* comb, const float* head,
                    const float* WO, const float* bO,
                    const unsigned char* padq, const unsigned char* padk,
                    bool causal, const float* resid, float* outR)
{
    // Wc[p,h] = comb[p] @ head[p,h]   -> [3,H,D,DK]
    gemm(st, GM_NN, false, comb, head, w.wc, nullptr, nullptr,
         cD, cDK, cDK, cDK, cDK, cDK,
         (long long)cD * cDK, 0,
         (long long)cH * cDK * cDK, (long long)cDK * cDK,
         (long long)cH * cD * cDK, (long long)cD * cDK, 3, cH);
    // Q/K/V [B,H,S,DK] = x @ Wc[p,h], batched over (b,h)
    const float* srcs[3] = {xq, xkv, xkv};
    float* dsts[3] = {w.Q, w.K, w.V};
    for (int p = 0; p < 3; ++p) {
        gemm(st, GM_NN, false, srcs[p], w.wc + (long long)p * cH * cD * cDK, dsts[p], nullptr, nullptr,
             cS, cDK, cD, cD, cDK, cDK,
             (long long)cS * cD, 0,
             0, (long long)cD * cDK,
             (long long)cH * cS * cDK, (long long)cS * cDK, cB, cH);
    }
    // scoresT[b,h,k,q] = K[b,h,k,:] . Q[b,h,q,:]   (NT), batched over b*h
    gemm(st, GM_NT, false, w.K, w.Q, w.sc, nullptr, nullptr,
         cS, cS, cDK, cDK, cDK, cS,
         (long long)cS * cDK, 0,
         (long long)cS * cDK, 0,
         (long long)cS * cS, 0, cB * cH, 1);
    // softmax over q (contiguous)
    {
        dim3 g(cB * cH * cS), blk(256);
        if (causal) softmax_kernel<true><<<g, blk, 0, st>>>(w.sc, padq, padk, 0.125f);
        else        softmax_kernel<false><<<g, blk, 0, st>>>(w.sc, padq, padk, 0.125f);
    }
    // att[b,q,h*DK+j] = sum_k scT[b,h,k,q] * V[b,h,k,j]   (TN), batched over (b,h)
    gemm(st, GM_TN, false, w.sc, w.V, w.att, nullptr, nullptr,
         cS, cDK, cS, cS, cDK, cD,
         (long long)cH * cS * cS, (long long)cS * cS,
         (long long)cH * cS * cDK, (long long)cS * cDK,
         (long long)cS * cD, cDK, cB, cH);
    // r = att @ WO + bO + resid
    gemm(st, GM_NN, false, w.att, WO, outR, bO, resid,
         cBS, cD, cD, cD, cD, cD, 0, 0, 0, 0, 0, 0, 1, 1);
}

extern "C" void kernel_launch(void* const* d_in, const int* in_sizes, int n_in,
                              void* d_out, int out_size, void* d_ws, size_t ws_size,
                              hipStream_t stream)
{
    const float* X       = (const float*)d_in[0];
    const float* outp    = (const float*)d_in[1];
    const float* e_comb  = (const float*)d_in[2];
    const float* e_head  = (const float*)d_in[3];
    const float* e_WO    = (const float*)d_in[4];
    const float* e_bO    = (const float*)d_in[5];
    const float* e_W1    = (const float*)d_in[6];
    const float* e_W2    = (const float*)d_in[7];
    const float* ds_comb = (const float*)d_in[8];
    const float* ds_head = (const float*)d_in[9];
    const float* ds_WO   = (const float*)d_in[10];
    const float* ds_bO   = (const float*)d_in[11];
    const float* dc_comb = (const float*)d_in[12];
    const float* dc_head = (const float*)d_in[13];
    const float* dc_WO   = (const float*)d_in[14];
    const float* dc_bO   = (const float*)d_in[15];
    const float* d_W1    = (const float*)d_in[16];
    const float* d_W2    = (const float*)d_in[17];
    float* Y = (float*)d_out;

    Ws w;
    float* p = (float*)d_ws;
    const long long NB = (long long)cBS * cD;          // 1,048,576 floats
    w.t0  = p; p += NB;                                // enc cur -> enc_repr
    w.t1  = p; p += NB;                                // n / n2 / an
    w.t2  = p; p += NB;                                // r / r2
    w.t3  = p; p += NB;                                // dec cur
    w.att = p; p += NB;
    w.Q   = p; p += NB;
    w.K   = p; p += NB;
    w.V   = p; p += NB;
    w.wc  = p; p += 3LL * cH * cD * cDK;               // 786,432
    w.ffn = p; p += (long long)cBS * cDFF;             // 4,194,304
    w.sc  = p; p += (long long)cB * cH * cS * cS;      // 16,777,216
    w.pin  = (unsigned char*)p;
    w.pout = w.pin + cB * cS;

    // ---- prep: pads + positional encodings ----
    pad_in_kernel <<<dim3(cB * cS), dim3(256), 0, stream>>>(X, w.pin);
    pad_dec_kernel<<<dim3(cB * cS), dim3(256), 0, stream>>>(outp, w.pout);
    posenc_enc_kernel<<<dim3(cB * cS), dim3(256), 0, stream>>>(X, w.t0);
    posenc_dec_kernel<<<dim3(cB * cS), dim3(256), 0, stream>>>(outp, w.t3);

    const long long LW3 = 3LL * cD * cDK;              // per-layer comb stride
    const long long LH3 = 3LL * cH * cDK * cDK;        // per-layer head stride
    const dim3 lnGrid(cS * cD / 256), lnBlk(256);

    // ---- encoder ----
    for (int i = 0; i < 2; ++i) {
        ln_kernel<<<lnGrid, lnBlk, 0, stream>>>(w.t0, w.t1);
        run_mha(stream, w, w.t1, w.t1, e_comb + i * LW3, e_head + i * LH3,
                e_WO + (long long)i * cD * cD, e_bO + i * cD,
                w.pin, w.pin, false, w.t1, w.t2);
        ln_kernel<<<lnGrid, lnBlk, 0, stream>>>(w.t2, w.t1);
        gemm(stream, GM_NN, true, w.t1, e_W1 + (long long)i * cD * cDFF, w.ffn, nullptr, nullptr,
             cBS, cDFF, cD, cD, cDFF, cDFF, 0, 0, 0, 0, 0, 0, 1, 1);
        gemm(stream, GM_NN, false, w.ffn, e_W2 + (long long)i * cDFF * cD, w.t0, nullptr, w.t1,
             cBS, cD, cDFF, cDFF, cD, cD, 0, 0, 0, 0, 0, 0, 1, 1);
    }
    // w.t0 now holds enc_repr

    // ---- decoder ----
    for (int i = 0; i < 2; ++i) {
        ln_kernel<<<lnGrid, lnBlk, 0, stream>>>(w.t3, w.t1);
        run_mha(stream, w, w.t1, w.t1, ds_comb + i * LW3, ds_head + i * LH3,
                ds_WO + (long long)i * cD * cD, ds_bO + i * cD,
                w.pin, w.pin, /*causal=*/true, w.t1, w.t2);      // pad_in both (preserved bug)
        ln_kernel<<<lnGrid, lnBlk, 0, stream>>>(w.t2, w.t1);
        run_mha(stream, w, w.t1, w.t0, dc_comb + i * LW3, dc_head + i * LH3,
                dc_WO + (long long)i * cD * cD, dc_bO + i * cD,
                w.pout, w.pin, /*causal=*/false, w.t1, w.t2);
        ln_kernel<<<lnGrid, lnBlk, 0, stream>>>(w.t2, w.t1);
        gemm(stream, GM_NN, true, w.t1, d_W1 + (long long)i * cD * cDFF, w.ffn, nullptr, nullptr,
             cBS, cDFF, cD, cD, cDFF, cDFF, 0, 0, 0, 0, 0, 0, 1, 1);
        gemm(stream, GM_NN, false, w.ffn, d_W2 + (long long)i * cDFF * cD, w.t3, nullptr, w.t1,
             cBS, cD, cDFF, cDFF, cD, cD, 0, 0, 0, 0, 0, 0, 1, 1);
    }

    final_kernel<<<dim3(cB * (cS - 1)), dim3(256), 0, stream>>>(w.t3, w.pout, Y);
}

// Round 2
// 2442.274 us; speedup vs baseline: 1.3356x; 1.3356x over previous
//
#include <hip/hip_runtime.h>
#include <cstdint>
#include <cstddef>

// Problem constants (fixed by the reference)
constexpr int cB = 2, cS = 1024, cD = 512, cH = 8, cDK = 64, cDFF = 2048;
constexpr int cBS = cB * cS;
constexpr float kNEG = -1e19f;

// ============================ SGEMM (fp32 vector) ============================
// C[M,N] = A op B, tiles BM=128 x BN(128|64), BK=16, 256 threads, 8x(BN/16) micro.
// MODE: 0 = NN (A[m][k], B[k][n]); 1 = TA (A[k][m], B[k][n]); 2 = TB (A[m][k], B[n][k]).
// Batched over z = ((g1*G2+g2)*KS + kc); split-K writes plane kc of C (parts buffer).
// bias/resid only valid when KS==1.
template<int BN, int MODE, bool GELU>
__global__ __launch_bounds__(256) void sgemm(
    const float* __restrict__ A, const float* __restrict__ B, float* __restrict__ C,
    const float* __restrict__ bias, const float* __restrict__ resid,
    int K, int KS, int G2, int lda, int ldb, int ldc,
    long long a1, long long a2, long long b1, long long b2,
    long long c1, long long c2, long long plane)
{
    constexpr int BM = 128, BK = 16;
    constexpr int AP = BM + 4, BP = BN + 4;
    constexpr int MN = BN / 16;                      // 8 or 4 cols per thread
    __shared__ float As[BK][AP];
    __shared__ float Bs[BK][BP];

    const int z = blockIdx.z;
    const int kc = z % KS;
    const int zz = z / KS;
    const int g1 = zz / G2, g2 = zz % G2;
    const float* Ab = A + (long long)g1 * a1 + (long long)g2 * a2;
    const float* Bb = B + (long long)g1 * b1 + (long long)g2 * b2;
    float* Cb = C + (long long)g1 * c1 + (long long)g2 * c2 + (long long)kc * plane;
    const int klen = K / KS, kbase = kc * klen;
    const int m0 = blockIdx.y * BM, n0 = blockIdx.x * BN;
    const int t = threadIdx.x, tx = t & 15, ty = t >> 4;

    float acc[8][MN];
    #pragma unroll
    for (int i = 0; i < 8; ++i)
        #pragma unroll
        for (int j = 0; j < MN; ++j) acc[i][j] = 0.f;

    for (int k0 = kbase; k0 < kbase + klen; k0 += BK) {
        // ---- stage A ----
        if (MODE == 1) {                              // TA: A stored [K][M]
            #pragma unroll
            for (int r = 0; r < 2; ++r) {
                const int c = r * 256 + t, kk = c >> 5, m4 = c & 31;
                float4 v = *(const float4*)&Ab[(long long)(k0 + kk) * lda + m0 + m4 * 4];
                *(float4*)&As[kk][m4 * 4] = v;
            }
        } else {                                      // NN: A stored [M][K]
            #pragma unroll
            for (int r = 0; r < 2; ++r) {
                const int c = r * 256 + t, kq = c & 3, mm = c >> 2;
                float4 v = *(const float4*)&Ab[(long long)(m0 + mm) * lda + k0 + kq * 4];
                As[kq * 4 + 0][mm] = v.x; As[kq * 4 + 1][mm] = v.y;
                As[kq * 4 + 2][mm] = v.z; As[kq * 4 + 3][mm] = v.w;
            }
        }
        // ---- stage B ----
        if (MODE == 2) {                              // TB: B stored [N][K]
            #pragma unroll
            for (int r = 0; r < BN / 64; ++r) {
                const int c = r * 256 + t, kq = c & 3, nn = c >> 2;
                float4 v = *(const float4*)&Bb[(long long)(n0 + nn) * ldb + k0 + kq * 4];
                Bs[kq * 4 + 0][nn] = v.x; Bs[kq * 4 + 1][nn] = v.y;
                Bs[kq * 4 + 2][nn] = v.z; Bs[kq * 4 + 3][nn] = v.w;
            }
        } else {                                      // NN: B stored [K][N]
            #pragma unroll
            for (int r = 0; r < BN / 64; ++r) {
                const int c = r * 256 + t, n4 = c & (BN / 4 - 1), kk = c / (BN / 4);
                float4 v = *(const float4*)&Bb[(long long)(k0 + kk) * ldb + n0 + n4 * 4];
                *(float4*)&Bs[kk][n4 * 4] = v;
            }
        }
        __syncthreads();
        #pragma unroll
        for (int kk = 0; kk < BK; ++kk) {
            float a[8], b[MN];
            *(float4*)&a[0] = *(const float4*)&As[kk][ty * 8];
            *(float4*)&a[4] = *(const float4*)&As[kk][ty * 8 + 4];
            if (MN == 8) {
                *(float4*)&b[0] = *(const float4*)&Bs[kk][tx * 8];
                *(float4*)&b[4] = *(const float4*)&Bs[kk][tx * 8 + 4];
            } else {
                *(float4*)&b[0] = *(const float4*)&Bs[kk][tx * 4];
            }
            #pragma unroll
            for (int i = 0; i < 8; ++i)
                #pragma unroll
                for (int j = 0; j < MN; ++j)
                    acc[i][j] = fmaf(a[i], b[j], acc[i][j]);
        }
        __syncthreads();
    }

    // ---- epilogue ----
    #pragma unroll
    for (int i = 0; i < 8; ++i) {
        const int row = m0 + ty * 8 + i;
        #pragma unroll
        for (int j4 = 0; j4 < MN / 4; ++j4) {
            const int col = n0 + tx * MN + j4 * 4;
            float4 v;
            v.x = acc[i][j4 * 4 + 0]; v.y = acc[i][j4 * 4 + 1];
            v.z = acc[i][j4 * 4 + 2]; v.w = acc[i][j4 * 4 + 3];
            if (bias) {
                v.x += bias[col + 0]; v.y += bias[col + 1];
                v.z += bias[col + 2]; v.w += bias[col + 3];
            }
            if (GELU) {
                v.x = 0.5f * v.x * (1.0f + erff(v.x * 0.70710678118654752440f));
                v.y = 0.5f * v.y * (1.0f + erff(v.y * 0.70710678118654752440f));
                v.z = 0.5f * v.z * (1.0f + erff(v.z * 0.70710678118654752440f));
                v.w = 0.5f * v.w * (1.0f + erff(v.w * 0.70710678118654752440f));
            }
            const long long idx = (long long)row * ldc + col;
            if (resid) {
                float4 rr = *(const float4*)&resid[idx];
                v.x += rr.x; v.y += rr.y; v.z += rr.z; v.w += rr.w;
            }
            *(float4*)&Cb[idx] = v;
        }
    }
}

// ============================ split-K reduce ============================
// out[i] = sum_z parts[z*plane + i] (+ bias[col]) (+ resid[i])
__global__ __launch_bounds__(256) void reduce_kernel(
    const float* __restrict__ parts, float* __restrict__ out, long long n,
    int ks, long long plane, const float* __restrict__ bias, int ldcMask,
    const float* __restrict__ resid)
{
    const long long i = ((long long)blockIdx.x * 256 + threadIdx.x) * 4;
    if (i >= n) return;
    float4 s = {0.f, 0.f, 0.f, 0.f};
    for (int z = 0; z < ks; ++z) {
        float4 v = *(const float4*)&parts[(long long)z * plane + i];
        s.x += v.x; s.y += v.y; s.z += v.z; s.w += v.w;
    }
    if (bias) {
        const int col = (int)(i & ldcMask);
        s.x += bias[col + 0]; s.y += bias[col + 1];
        s.z += bias[col + 2]; s.w += bias[col + 3];
    }
    if (resid) {
        float4 rr = *(const float4*)&resid[i];
        s.x += rr.x; s.y += rr.y; s.z += rr.z; s.w += rr.w;
    }
    *(float4*)&out[i] = s;
}

// ============================ Wc3 = comb @ head (per p,h) ============================
// Wc3[d][p*512 + h*64 + j] = sum_k comb[p][d][k] * head[p][h][k][j]
__global__ __launch_bounds__(256) void wct_kernel(
    const float* __restrict__ comb, const float* __restrict__ head, float* __restrict__ Wc3)
{
    __shared__ float Hs[64 * 64];
    const int ph = blockIdx.x;            // p*8 + h
    const int p = ph >> 3, h = ph & 7;
    const int t = threadIdx.x;
    for (int i = t; i < 4096; i += 256) Hs[i] = head[(long long)ph * 4096 + i];
    __syncthreads();
    const int j = t & 63, dg = t >> 6;
    const int d0 = blockIdx.y * 128;
    const float* cb = comb + (long long)p * 512 * 64;
    for (int dd = 0; dd < 128; dd += 4) {
        const int d = d0 + dd + dg;
        float s = 0.f;
        #pragma unroll 4
        for (int kk = 0; kk < 64; ++kk)
            s = fmaf(cb[d * 64 + kk], Hs[kk * 64 + j], s);
        Wc3[(long long)d * 1536 + p * 512 + h * 64 + j] = s;
    }
}

// ============================ softmax over QUERY dim (verbatim, passed R1) ============================
template<bool CAUSAL>
__global__ __launch_bounds__(256) void softmax_kernel(
    float* __restrict__ sc, const unsigned char* __restrict__ padq,
    const unsigned char* __restrict__ padk, float scale)
{
    const int r = blockIdx.x;             // (b*H + h)*S + k
    const int k = r & (cS - 1);
    const int b = r / (cH * cS);
    float* row = sc + (long long)r * cS;
    const bool pk = padk[b * cS + k] != 0;
    const int tid = threadIdx.x;
    float4 v4 = reinterpret_cast<const float4*>(row)[tid];
    float vals[4] = {v4.x, v4.y, v4.z, v4.w};
    #pragma unroll
    for (int u = 0; u < 4; ++u) {
        const int q = tid * 4 + u;
        bool masked = pk || (padq[b * cS + q] != 0);
        if (CAUSAL) masked = masked || (q < k);
        float x = vals[u];
        if (masked) x += kNEG;
        if (!CAUSAL) x *= scale;
        vals[u] = x;
    }
    float m = fmaxf(fmaxf(vals[0], vals[1]), fmaxf(vals[2], vals[3]));
    #pragma unroll
    for (int off = 32; off > 0; off >>= 1) m = fmaxf(m, __shfl_down(m, off));
    __shared__ float red[8];
    if ((tid & 63) == 0) red[tid >> 6] = m;
    __syncthreads();
    const float rm = fmaxf(fmaxf(red[0], red[1]), fmaxf(red[2], red[3]));
    float e[4], s = 0.f;
    #pragma unroll
    for (int u = 0; u < 4; ++u) { e[u] = expf(vals[u] - rm); s += e[u]; }
    #pragma unroll
    for (int off = 32; off > 0; off >>= 1) s += __shfl_down(s, off);
    if ((tid & 63) == 0) red[4 + (tid >> 6)] = s;
    __syncthreads();
    float inv = 1.0f / (red[4] + red[5] + red[6] + red[7]);
    if (CAUSAL) inv *= scale;
    v4.x = e[0] * inv; v4.y = e[1] * inv; v4.z = e[2] * inv; v4.w = e[3] * inv;
    reinterpret_cast<float4*>(row)[tid] = v4;
}

// ============================ batch-dim layer norm (B=2 closed form) ============================
__global__ __launch_bounds__(256) void ln_kernel(const float* __restrict__ x, float* __restrict__ out)
{
    const long long idx = (long long)blockIdx.x * 256 + threadIdx.x;
    const float x0 = x[idx], x1 = x[idx + (long long)cS * cD];
    const float diff = x0 - x1;
    const float stdv = fabsf(diff) * 0.70710678118654752440f;
    const float o = (0.5f * diff) / (stdv + 1e-4f);
    out[idx] = o;
    out[idx + (long long)cS * cD] = -o;
}

// ============================ padding masks ============================
__global__ __launch_bounds__(256) void pad_in_kernel(const float* __restrict__ X, unsigned char* __restrict__ pad)
{
    const int r = blockIdx.x;
    const float* row = X + (long long)r * cD;
    const int tid = threadIdx.x;
    const bool nz = (row[tid] != 0.f) | (row[tid + 256] != 0.f);
    unsigned long long w = __ballot(nz);
    __shared__ unsigned long long sh[4];
    if ((tid & 63) == 0) sh[tid >> 6] = w;
    __syncthreads();
    if (tid == 0) pad[r] = ((sh[0] | sh[1] | sh[2] | sh[3]) == 0ULL) ? 1 : 0;
}

__global__ __launch_bounds__(256) void pad_dec_kernel(const float* __restrict__ outp, unsigned char* __restrict__ pad)
{
    const int r = blockIdx.x;
    const int s = r & (cS - 1);
    const int b = r >> 10;
    if (s == 0) { if (threadIdx.x == 0) pad[r] = 0; return; }
    const float* row = outp + ((long long)b * (cS - 1) + (s - 1)) * cD;
    const int tid = threadIdx.x;
    const bool nz = (row[tid] != 0.f) | (row[tid + 256] != 0.f);
    unsigned long long w = __ballot(nz);
    __shared__ unsigned long long sh[4];
    if ((tid & 63) == 0) sh[tid >> 6] = w;
    __syncthreads();
    if (tid == 0) pad[r] = ((sh[0] | sh[1] | sh[2] | sh[3]) == 0ULL) ? 1 : 0;
}

// ============================ positional encoding ============================
__device__ __forceinline__ float pe_val(int s, int d)
{
    const int i2 = d & ~1;
    const float dv = powf(10000.0f, -(float)i2 / (float)cD);
    const float ang = (float)s * dv;
    return (d & 1) ? cosf(ang) : sinf(ang);
}

__global__ __launch_bounds__(256) void posenc_enc_kernel(const float* __restrict__ X, float* __restrict__ out)
{
    const int r = blockIdx.x;
    const int s = r & (cS - 1);
    const int tid = threadIdx.x;
    #pragma unroll
    for (int u = 0; u < 2; ++u) {
        const int d = tid + 256 * u;
        out[(long long)r * cD + d] = X[(long long)r * cD + d] + pe_val(s, d);
    }
}

__global__ __launch_bounds__(256) void posenc_dec_kernel(const float* __restrict__ outp, float* __restrict__ out)
{
    const int r = blockIdx.x;
    const int s = r & (cS - 1);
    const int b = r >> 10;
    const int tid = threadIdx.x;
    #pragma unroll
    for (int u = 0; u < 2; ++u) {
        const int d = tid + 256 * u;
        const float base = (s == 0) ? 1.0f : outp[((long long)b * (cS - 1) + (s - 1)) * cD + d];
        out[(long long)r * cD + d] = base + pe_val(s, d);
    }
}

// ============================ final masked slice ============================
__global__ __launch_bounds__(256) void final_kernel(const float* __restrict__ cur,
                                                    const unsigned char* __restrict__ pad,
                                                    float* __restrict__ out)
{
    const int r = blockIdx.x;
    const int b = r / (cS - 1);
    const int s = r - b * (cS - 1) + 1;
    const int tid = threadIdx.x;
    const bool p = pad[b * cS + s] != 0;
    #pragma unroll
    for (int u = 0; u < 2; ++u) {
        const int d = tid + 256 * u;
        out[(long long)r * cD + d] = p ? 0.0f : cur[((long long)b * cS + s) * cD + d];
    }
}

// ============================ host orchestration ============================
struct Ws {
    float *t0, *t1, *t2, *t3, *wc3, *qkv, *att, *parts, *sc, *ffn;
    unsigned char *pin, *pout;
};

// one MHA: xq (fp32 [2048,512]), xkv; if xq==xkv a single fused QKV gemm.
static void run_mha(hipStream_t st, const Ws& w,
                    const float* xq, const float* xkv,
                    const float* comb, const float* head,
                    const float* WO, const float* bO,
                    const unsigned char* padq, const unsigned char* padk,
                    bool causal, const float* resid, float* outR)
{
    const long long M1 = 1048576;       // 2048*512 / 1024*1024 strides
    // Wc3
    wct_kernel<<<dim3(24, 4), 256, 0, st>>>(comb, head, w.wc3);
    // QKV (NN): C = [2048][1536]
    if (xq == xkv) {
        sgemm<128, 0, false><<<dim3(12, 16, 1), 256, 0, st>>>(
            xq, w.wc3, w.qkv, nullptr, nullptr, 512, 1, 1, 512, 1536, 1536,
            0, 0, 0, 0, 0, 0, 0);
    } else {
        sgemm<128, 0, false><<<dim3(4, 16, 1), 256, 0, st>>>(
            xq, w.wc3, w.qkv, nullptr, nullptr, 512, 1, 1, 512, 1536, 1536,
            0, 0, 0, 0, 0, 0, 0);
        sgemm<128, 0, false><<<dim3(8, 16, 1), 256, 0, st>>>(
            xkv, w.wc3 + 512, w.qkv + 512, nullptr, nullptr, 512, 1, 1, 512, 1536, 1536,
            0, 0, 0, 0, 0, 0, 0);
    }
    // scores (TB): scT[b,h][k][q] = K . Q ; A=K_all (qkv+512), B=Q_all (qkv+0)
    sgemm<128, 2, false><<<dim3(8, 8, 16), 256, 0, st>>>(
        w.qkv + 512, w.qkv, w.sc, nullptr, nullptr, 64, 1, 8, 1536, 1536, 1024,
        1024LL * 1536, 64, 1024LL * 1536, 64, 8 * M1, M1, 0);
    // softmax over q
    {
        dim3 g(cB * cH * cS), blk(256);
        if (causal) softmax_kernel<true><<<g, blk, 0, st>>>(w.sc, padq, padk, 0.125f);
        else        softmax_kernel<false><<<g, blk, 0, st>>>(w.sc, padq, padk, 0.125f);
    }
    // PV (TA x NN, split-K=4): att[b*1024+q][h*64+j] = sum_k P[k][q] * V[k][j]
    sgemm<64, 1, false><<<dim3(1, 8, 64), 256, 0, st>>>(
        w.sc, w.qkv + 1024, w.parts, nullptr, nullptr, 1024, 4, 8, 1024, 1536, 512,
        8 * M1, M1, 1024LL * 1536, 64, 1024LL * 512, 64, M1);
    reduce_kernel<<<dim3(1024), 256, 0, st>>>(w.parts, w.att, M1, 4, M1, nullptr, 511, nullptr);
    // WO (NN, split-K=4): r = att @ WO + bO + resid
    sgemm<128, 0, false><<<dim3(4, 16, 4), 256, 0, st>>>(
        w.att, WO, w.parts, nullptr, nullptr, 512, 4, 1, 512, 512, 512,
        0, 0, 0, 0, 0, 0, M1);
    reduce_kernel<<<dim3(1024), 256, 0, st>>>(w.parts, outR, M1, 4, M1, bO, 511, resid);
}

extern "C" void kernel_launch(void* const* d_in, const int* in_sizes, int n_in,
                              void* d_out, int out_size, void* d_ws, size_t ws_size,
                              hipStream_t stream)
{
    const float* X       = (const float*)d_in[0];
    const float* outp    = (const float*)d_in[1];
    const float* e_comb  = (const float*)d_in[2];
    const float* e_head  = (const float*)d_in[3];
    const float* e_WO    = (const float*)d_in[4];
    const float* e_bO    = (const float*)d_in[5];
    const float* e_W1    = (const float*)d_in[6];
    const float* e_W2    = (const float*)d_in[7];
    const float* ds_comb = (const float*)d_in[8];
    const float* ds_head = (const float*)d_in[9];
    const float* ds_WO   = (const float*)d_in[10];
    const float* ds_bO   = (const float*)d_in[11];
    const float* dc_comb = (const float*)d_in[12];
    const float* dc_head = (const float*)d_in[13];
    const float* dc_WO   = (const float*)d_in[14];
    const float* dc_bO   = (const float*)d_in[15];
    const float* d_W1    = (const float*)d_in[16];
    const float* d_W2    = (const float*)d_in[17];
    float* Y = (float*)d_out;

    Ws w;
    float* p = (float*)d_ws;
    const long long M1 = 1048576;
    w.t0   = p; p += M1;
    w.t1   = p; p += M1;
    w.t2   = p; p += M1;
    w.t3   = p; p += M1;
    w.wc3  = p; p += 512 * 1536;            // 786,432
    w.qkv  = p; p += 2048LL * 1536;         // 3,145,728
    w.att  = p; p += M1;
    w.parts= p; p += 4 * M1;                // split-K partials (max KS=4, plane 1M)
    w.sc   = p; p += 16LL * M1;             // 64 MB scores; ffn overlays it
    w.ffn  = w.sc;                          // [2048][2048] fp32 (attention finished)
    w.pin  = (unsigned char*)p;
    w.pout = w.pin + cB * cS;

    // ---- prep ----
    pad_in_kernel <<<dim3(cB * cS), 256, 0, stream>>>(X, w.pin);
    pad_dec_kernel<<<dim3(cB * cS), 256, 0, stream>>>(outp, w.pout);
    posenc_enc_kernel<<<dim3(cB * cS), 256, 0, stream>>>(X, w.t0);
    posenc_dec_kernel<<<dim3(cB * cS), 256, 0, stream>>>(outp, w.t3);

    const long long LW3 = 3LL * cD * cDK;   // per-layer comb stride (98304)
    const long long LH3 = 3LL * cH * cDK * cDK;
    const dim3 lnGrid(cS * cD / 256);

    // ---- encoder ----
    for (int i = 0; i < 2; ++i) {
        ln_kernel<<<lnGrid, 256, 0, stream>>>(w.t0, w.t1);
        run_mha(stream, w, w.t1, w.t1, e_comb + i * LW3, e_head + i * LH3,
                e_WO + (long long)i * cD * cD, e_bO + i * cD,
                w.pin, w.pin, false, w.t1, w.t2);
        ln_kernel<<<lnGrid, 256, 0, stream>>>(w.t2, w.t1);
        // FFN1: gelu(an @ W1) -> ffn
        sgemm<128, 0, true><<<dim3(16, 16, 1), 256, 0, stream>>>(
            w.t1, e_W1 + (long long)i * cD * cDFF, w.ffn, nullptr, nullptr,
            512, 1, 1, 512, 2048, 2048, 0, 0, 0, 0, 0, 0, 0);
        // FFN2 (split-K=4): cur = ffn @ W2 + an
        sgemm<128, 0, false><<<dim3(4, 16, 4), 256, 0, stream>>>(
            w.ffn, e_W2 + (long long)i * cDFF * cD, w.parts, nullptr, nullptr,
            2048, 4, 1, 2048, 512, 512, 0, 0, 0, 0, 0, 0, M1);
        reduce_kernel<<<dim3(1024), 256, 0, stream>>>(w.parts, w.t0, M1, 4, M1, nullptr, 511, w.t1);
    }
    // w.t0 = enc_repr

    // ---- decoder ----
    for (int i = 0; i < 2; ++i) {
        ln_kernel<<<lnGrid, 256, 0, stream>>>(w.t3, w.t1);
        run_mha(stream, w, w.t1, w.t1, ds_comb + i * LW3, ds_head + i * LH3,
                ds_WO + (long long)i * cD * cD, ds_bO + i * cD,
                w.pin, w.pin, /*causal=*/true, w.t1, w.t2);     // pad_in both (preserved bug)
        ln_kernel<<<lnGrid, 256, 0, stream>>>(w.t2, w.t1);
        run_mha(stream, w, w.t1, w.t0, dc_comb + i * LW3, dc_head + i * LH3,
                dc_WO + (long long)i * cD * cD, dc_bO + i * cD,
                w.pout, w.pin, /*causal=*/false, w.t1, w.t2);
        ln_kernel<<<lnGrid, 256, 0, stream>>>(w.t2, w.t1);
        sgemm<128, 0, true><<<dim3(16, 16, 1), 256, 0, stream>>>(
            w.t1, d_W1 + (long long)i * cD * cDFF, w.ffn, nullptr, nullptr,
            512, 1, 1, 512, 2048, 2048, 0, 0, 0, 0, 0, 0, 0);
        sgemm<128, 0, false><<<dim3(4, 16, 4), 256, 0, stream>>>(
            w.ffn, d_W2 + (long long)i * cDFF * cD, w.parts, nullptr, nullptr,
            2048, 4, 1, 2048, 512, 512, 0, 0, 0, 0, 0, 0, M1);
        reduce_kernel<<<dim3(1024), 256, 0, stream>>>(w.parts, w.t3, M1, 4, M1, nullptr, 511, w.t1);
    }

    final_kernel<<<dim3(cB * (cS - 1)), 256, 0, stream>>>(w.t3, w.pout, Y);
}

// Round 4
// 1979.408 us; speedup vs baseline: 1.6479x; 1.2338x over previous
//
#include <hip/hip_runtime.h>
#include <cstdint>
#include <cstddef>

// Problem constants (fixed by the reference)
constexpr int cB = 2, cS = 1024, cD = 512, cH = 8, cDK = 64, cDFF = 2048;
constexpr int cBS = cB * cS;
constexpr float kNEG = -1e19f;

// ============================ SGEMM (fp32 vector) ============================
// Tile BM=128 x BN=64, BK=16, 256 threads, 8x4 microtile.
// MODE: 0 = NN (A[m][k], B[k][n]); 1 = TA (A[k][m], B[k][n]); 2 = TB (A[m][k], B[n][k]).
// z = ((g1*G2+g2)*KS + kc); split-K (KS>1) writes compact plane kc (caller passes ldc=N).
// bias/resid only when KS==1.
template<int MODE, bool GELU>
__global__ __launch_bounds__(256) void sgemm(
    const float* __restrict__ A, const float* __restrict__ B, float* __restrict__ C,
    const float* __restrict__ bias, const float* __restrict__ resid,
    int K, int KS, int G2, int lda, int ldb, int ldc,
    long long a1, long long a2, long long b1, long long b2,
    long long c1, long long c2, long long plane)
{
    constexpr int BM = 128, BN = 64, BK = 16;
    constexpr int AP = BM + 4, BP = BN + 4;
    __shared__ float As[BK][AP];
    __shared__ float Bs[BK][BP];

    const int z = blockIdx.z;
    const int kc = z % KS;
    const int zz = z / KS;
    const int g1 = zz / G2, g2 = zz % G2;
    const float* Ab = A + (long long)g1 * a1 + (long long)g2 * a2;
    const float* Bb = B + (long long)g1 * b1 + (long long)g2 * b2;
    float* Cb = C + (long long)g1 * c1 + (long long)g2 * c2 + (long long)kc * plane;
    const int klen = K / KS, kbase = kc * klen;
    const int m0 = blockIdx.y * BM, n0 = blockIdx.x * BN;
    const int t = threadIdx.x, tx = t & 15, ty = t >> 4;

    float acc[8][4];
    #pragma unroll
    for (int i = 0; i < 8; ++i)
        #pragma unroll
        for (int j = 0; j < 4; ++j) acc[i][j] = 0.f;

    for (int k0 = kbase; k0 < kbase + klen; k0 += BK) {
        // ---- stage A (128x16 = 2 float4/thread) ----
        if (MODE == 1) {                              // TA: A stored [K][M]
            #pragma unroll
            for (int r = 0; r < 2; ++r) {
                const int c = r * 256 + t, kk = c >> 5, m4 = c & 31;
                *(float4*)&As[kk][m4 * 4] =
                    *(const float4*)&Ab[(long long)(k0 + kk) * lda + m0 + m4 * 4];
            }
        } else {                                      // A stored [M][K]
            #pragma unroll
            for (int r = 0; r < 2; ++r) {
                const int c = r * 256 + t, kq = c & 3, mm = c >> 2;
                float4 v = *(const float4*)&Ab[(long long)(m0 + mm) * lda + k0 + kq * 4];
                As[kq * 4 + 0][mm] = v.x; As[kq * 4 + 1][mm] = v.y;
                As[kq * 4 + 2][mm] = v.z; As[kq * 4 + 3][mm] = v.w;
            }
        }
        // ---- stage B (64x16 = 1 float4/thread) ----
        if (MODE == 2) {                              // TB: B stored [N][K]
            const int kq = t & 3, nn = t >> 2;
            float4 v = *(const float4*)&Bb[(long long)(n0 + nn) * ldb + k0 + kq * 4];
            Bs[kq * 4 + 0][nn] = v.x; Bs[kq * 4 + 1][nn] = v.y;
            Bs[kq * 4 + 2][nn] = v.z; Bs[kq * 4 + 3][nn] = v.w;
        } else {                                      // B stored [K][N]
            const int n4 = t & 15, kk = t >> 4;
            *(float4*)&Bs[kk][n4 * 4] =
                *(const float4*)&Bb[(long long)(k0 + kk) * ldb + n0 + n4 * 4];
        }
        __syncthreads();
        #pragma unroll
        for (int kk = 0; kk < BK; ++kk) {
            float4 b4 = *(const float4*)&Bs[kk][tx * 4];     // 2-addr/bank: free
            float4 a0 = *(const float4*)&As[kk][ty * 8];     // 4-addr broadcast: free
            float4 a1v = *(const float4*)&As[kk][ty * 8 + 4];
            const float a[8] = {a0.x, a0.y, a0.z, a0.w, a1v.x, a1v.y, a1v.z, a1v.w};
            const float b[4] = {b4.x, b4.y, b4.z, b4.w};
            #pragma unroll
            for (int i = 0; i < 8; ++i)
                #pragma unroll
                for (int j = 0; j < 4; ++j)
                    acc[i][j] = fmaf(a[i], b[j], acc[i][j]);
        }
        __syncthreads();
    }

    // ---- epilogue ----
    #pragma unroll
    for (int i = 0; i < 8; ++i) {
        const int row = m0 + ty * 8 + i;
        const int col = n0 + tx * 4;
        float4 v;
        v.x = acc[i][0]; v.y = acc[i][1]; v.z = acc[i][2]; v.w = acc[i][3];
        if (bias) {
            v.x += bias[col + 0]; v.y += bias[col + 1];
            v.z += bias[col + 2]; v.w += bias[col + 3];
        }
        if (GELU) {
            v.x = 0.5f * v.x * (1.0f + erff(v.x * 0.70710678118654752440f));
            v.y = 0.5f * v.y * (1.0f + erff(v.y * 0.70710678118654752440f));
            v.z = 0.5f * v.z * (1.0f + erff(v.z * 0.70710678118654752440f));
            v.w = 0.5f * v.w * (1.0f + erff(v.w * 0.70710678118654752440f));
        }
        const long long idx = (long long)row * ldc + col;
        if (resid) {
            float4 rr = *(const float4*)&resid[idx];
            v.x += rr.x; v.y += rr.y; v.z += rr.z; v.w += rr.w;
        }
        *(float4*)&Cb[idx] = v;
    }
}

// ============================ split-K reduces ============================
// flat: out[i] = sum_z parts[z*plane+i] (+bias[i&ldcMask]) (+resid[i])
__global__ __launch_bounds__(256) void reduce_flat(
    const float* __restrict__ parts, float* __restrict__ out, long long n,
    int ks, long long plane, const float* __restrict__ bias, int ldcMask,
    const float* __restrict__ resid)
{
    const long long i = ((long long)blockIdx.x * 256 + threadIdx.x) * 4;
    if (i >= n) return;
    float4 s = {0.f, 0.f, 0.f, 0.f};
    for (int z = 0; z < ks; ++z) {
        float4 v = *(const float4*)&parts[(long long)z * plane + i];
        s.x += v.x; s.y += v.y; s.z += v.z; s.w += v.w;
    }
    if (bias) {
        const int col = (int)(i & ldcMask);
        s.x += bias[col + 0]; s.y += bias[col + 1];
        s.z += bias[col + 2]; s.w += bias[col + 3];
    }
    if (resid) {
        float4 rr = *(const float4*)&resid[i];
        s.x += rr.x; s.y += rr.y; s.z += rr.z; s.w += rr.w;
    }
    *(float4*)&out[i] = s;
}

// scatter: compact [M][N](pow2 N) planes -> out[row*ldcOut + colBase + col]
__global__ __launch_bounds__(256) void reduce_scatter(
    const float* __restrict__ parts, float* __restrict__ out, long long n,
    int ks, long long plane, int logN, int maskN, int ldcOut, int colBase)
{
    const long long i = ((long long)blockIdx.x * 256 + threadIdx.x) * 4;
    if (i >= n) return;
    float4 s = {0.f, 0.f, 0.f, 0.f};
    for (int z = 0; z < ks; ++z) {
        float4 v = *(const float4*)&parts[(long long)z * plane + i];
        s.x += v.x; s.y += v.y; s.z += v.z; s.w += v.w;
    }
    const long long row = i >> logN;
    const int col = (int)(i & maskN);
    *(float4*)&out[row * ldcOut + colBase + col] = s;
}

// ============================ Wc3 for all 6 MHAs, one dispatch ============================
// Wc3[z][d][p*512 + h*64 + j] = sum_k comb[p][d][k] * head[p][h][k][j]
__global__ __launch_bounds__(256) void wct_kernel(
    const float* __restrict__ ec, const float* __restrict__ eh,
    const float* __restrict__ dsc, const float* __restrict__ dsh,
    const float* __restrict__ dcc, const float* __restrict__ dch,
    float* __restrict__ Wc3)
{
    constexpr long long LWH = 3LL * 512 * 64;          // == 3*8*64*64
    __shared__ float Hs[64 * 64];
    const int zi = blockIdx.z;                         // 0..5
    const int l = zi & 1;
    const float* comb = (zi < 2) ? ec : (zi < 4) ? dsc : dcc;
    const float* head = (zi < 2) ? eh : (zi < 4) ? dsh : dch;
    comb += l * LWH; head += l * LWH;
    float* out = Wc3 + (long long)zi * 512 * 1536;

    const int ph = blockIdx.x;                         // p*8 + h
    const int p = ph >> 3, h = ph & 7;
    const int t = threadIdx.x;
    for (int i = t; i < 4096; i += 256) Hs[i] = head[(long long)ph * 4096 + i];
    __syncthreads();
    const int j = t & 63, dg = t >> 6;
    const int d0 = blockIdx.y * 128;
    const float* cb = comb + (long long)p * 512 * 64;
    for (int dd = 0; dd < 128; dd += 4) {
        const int d = d0 + dd + dg;
        float s = 0.f;
        #pragma unroll 4
        for (int kk = 0; kk < 64; ++kk)
            s = fmaf(cb[d * 64 + kk], Hs[kk * 64 + j], s);
        out[(long long)d * 1536 + p * 512 + h * 64 + j] = s;
    }
}

// ============================ softmax over QUERY dim ============================
template<bool CAUSAL>
__global__ __launch_bounds__(256) void softmax_kernel(
    float* __restrict__ sc, const unsigned char* __restrict__ padq,
    const unsigned char* __restrict__ padk, float scale)
{
    const int r = blockIdx.x;             // (b*H + h)*S + k
    const int k = r & (cS - 1);
    const int b = r / (cH * cS);
    float* row = sc + (long long)r * cS;
    const bool pk = padk[b * cS + k] != 0;
    const int tid = threadIdx.x;
    float4 v4 = reinterpret_cast<const float4*>(row)[tid];
    float vals[4] = {v4.x, v4.y, v4.z, v4.w};
    #pragma unroll
    for (int u = 0; u < 4; ++u) {
        const int q = tid * 4 + u;
        bool masked = pk || (padq[b * cS + q] != 0);
        if (CAUSAL) masked = masked || (q < k);
        float x = vals[u];
        if (masked) x += kNEG;
        if (!CAUSAL) x *= scale;
        vals[u] = x;
    }
    float m = fmaxf(fmaxf(vals[0], vals[1]), fmaxf(vals[2], vals[3]));
    #pragma unroll
    for (int off = 32; off > 0; off >>= 1) m = fmaxf(m, __shfl_down(m, off));
    __shared__ float red[8];
    if ((tid & 63) == 0) red[tid >> 6] = m;
    __syncthreads();
    const float rm = fmaxf(fmaxf(red[0], red[1]), fmaxf(red[2], red[3]));
    float e[4], s = 0.f;
    #pragma unroll
    for (int u = 0; u < 4; ++u) { e[u] = expf(vals[u] - rm); s += e[u]; }
    #pragma unroll
    for (int off = 32; off > 0; off >>= 1) s += __shfl_down(s, off);
    if ((tid & 63) == 0) red[4 + (tid >> 6)] = s;
    __syncthreads();
    float inv = 1.0f / (red[4] + red[5] + red[6] + red[7]);
    if (CAUSAL) inv *= scale;
    v4.x = e[0] * inv; v4.y = e[1] * inv; v4.z = e[2] * inv; v4.w = e[3] * inv;
    reinterpret_cast<float4*>(row)[tid] = v4;
}

// ============================ batch-dim layer norm (B=2 closed form) ============================
__global__ __launch_bounds__(256) void ln_kernel(const float* __restrict__ x, float* __restrict__ out)
{
    const long long idx = ((long long)blockIdx.x * 256 + threadIdx.x) * 4;
    float4 x0 = *(const float4*)&x[idx];
    float4 x1 = *(const float4*)&x[idx + (long long)cS * cD];
    float4 o;
    {
        const float d0 = x0.x - x1.x; o.x = (0.5f * d0) / (fabsf(d0) * 0.70710678f + 1e-4f);
        const float d1 = x0.y - x1.y; o.y = (0.5f * d1) / (fabsf(d1) * 0.70710678f + 1e-4f);
        const float d2 = x0.z - x1.z; o.z = (0.5f * d2) / (fabsf(d2) * 0.70710678f + 1e-4f);
        const float d3 = x0.w - x1.w; o.w = (0.5f * d3) / (fabsf(d3) * 0.70710678f + 1e-4f);
    }
    *(float4*)&out[idx] = o;
    float4 n;
    n.x = -o.x; n.y = -o.y; n.z = -o.z; n.w = -o.w;
    *(float4*)&out[idx + (long long)cS * cD] = n;
}

// ============================ padding masks ============================
__global__ __launch_bounds__(256) void pad_in_kernel(const float* __restrict__ X, unsigned char* __restrict__ pad)
{
    const int r = blockIdx.x;
    const float* row = X + (long long)r * cD;
    const int tid = threadIdx.x;
    const bool nz = (row[tid] != 0.f) | (row[tid + 256] != 0.f);
    unsigned long long w = __ballot(nz);
    __shared__ unsigned long long sh[4];
    if ((tid & 63) == 0) sh[tid >> 6] = w;
    __syncthreads();
    if (tid == 0) pad[r] = ((sh[0] | sh[1] | sh[2] | sh[3]) == 0ULL) ? 1 : 0;
}

__global__ __launch_bounds__(256) void pad_dec_kernel(const float* __restrict__ outp, unsigned char* __restrict__ pad)
{
    const int r = blockIdx.x;
    const int s = r & (cS - 1);
    const int b = r >> 10;
    if (s == 0) { if (threadIdx.x == 0) pad[r] = 0; return; }
    const float* row = outp + ((long long)b * (cS - 1) + (s - 1)) * cD;
    const int tid = threadIdx.x;
    const bool nz = (row[tid] != 0.f) | (row[tid + 256] != 0.f);
    unsigned long long w = __ballot(nz);
    __shared__ unsigned long long sh[4];
    if ((tid & 63) == 0) sh[tid >> 6] = w;
    __syncthreads();
    if (tid == 0) pad[r] = ((sh[0] | sh[1] | sh[2] | sh[3]) == 0ULL) ? 1 : 0;
}

// ============================ positional encoding ============================
__device__ __forceinline__ float pe_val(int s, int d)
{
    const int i2 = d & ~1;
    const float dv = powf(10000.0f, -(float)i2 / (float)cD);
    const float ang = (float)s * dv;
    return (d & 1) ? cosf(ang) : sinf(ang);
}

__global__ __launch_bounds__(256) void posenc_enc_kernel(const float* __restrict__ X, float* __restrict__ out)
{
    const int r = blockIdx.x;
    const int s = r & (cS - 1);
    const int tid = threadIdx.x;
    #pragma unroll
    for (int u = 0; u < 2; ++u) {
        const int d = tid + 256 * u;
        out[(long long)r * cD + d] = X[(long long)r * cD + d] + pe_val(s, d);
    }
}

__global__ __launch_bounds__(256) void posenc_dec_kernel(const float* __restrict__ outp, float* __restrict__ out)
{
    const int r = blockIdx.x;
    const int s = r & (cS - 1);
    const int b = r >> 10;
    const int tid = threadIdx.x;
    #pragma unroll
    for (int u = 0; u < 2; ++u) {
        const int d = tid + 256 * u;
        const float base = (s == 0) ? 1.0f : outp[((long long)b * (cS - 1) + (s - 1)) * cD + d];
        out[(long long)r * cD + d] = base + pe_val(s, d);
    }
}

// ============================ final masked slice ============================
__global__ __launch_bounds__(256) void final_kernel(const float* __restrict__ cur,
                                                    const unsigned char* __restrict__ pad,
                                                    float* __restrict__ out)
{
    const int r = blockIdx.x;
    const int b = r / (cS - 1);
    const int s = r - b * (cS - 1) + 1;
    const int tid = threadIdx.x;
    const bool p = pad[b * cS + s] != 0;
    #pragma unroll
    for (int u = 0; u < 2; ++u) {
        const int d = tid + 256 * u;
        out[(long long)r * cD + d] = p ? 0.0f : cur[((long long)b * cS + s) * cD + d];
    }
}

// ============================ host orchestration ============================
struct Ws {
    float *t0, *t1, *t2, *t3, *wc3a, *qkv, *att, *parts, *sc, *ffn;
    unsigned char *pin, *pout;
};

static void run_mha(hipStream_t st, const Ws& w, int mhaIdx,
                    const float* xq, const float* xkv,
                    const float* WO, const float* bO,
                    const unsigned char* padq, const unsigned char* padk,
                    bool causal, const float* resid, float* outR)
{
    const long long M1 = 1048576;
    const float* wc3 = w.wc3a + (long long)mhaIdx * 512 * 1536;
    if (xq == xkv) {
        // fused QKV (NN): [2048][1536], grid 384
        sgemm<0, false><<<dim3(24, 16, 1), 256, 0, st>>>(
            xq, wc3, w.qkv, nullptr, nullptr, 512, 1, 1, 512, 1536, 1536,
            0, 0, 0, 0, 0, 0, 0);
    } else {
        // cross: Q from xq (split-K=4, compact), K/V from xkv (split-K=2, compact)
        sgemm<0, false><<<dim3(8, 16, 4), 256, 0, st>>>(
            xq, wc3, w.parts, nullptr, nullptr, 512, 4, 1, 512, 1536, 512,
            0, 0, 0, 0, 0, 0, M1);
        reduce_scatter<<<dim3(1024), 256, 0, st>>>(w.parts, w.qkv, M1, 4, M1, 9, 511, 1536, 0);
        sgemm<0, false><<<dim3(16, 16, 2), 256, 0, st>>>(
            xkv, wc3 + 512, w.parts, nullptr, nullptr, 512, 2, 1, 512, 1536, 1024,
            0, 0, 0, 0, 0, 0, 2 * M1);
        reduce_scatter<<<dim3(2048), 256, 0, st>>>(w.parts, w.qkv, 2 * M1, 2, 2 * M1, 10, 1023, 1536, 512);
    }
    // scoresT[b,h][k][q] = K . Q (TB), grid 2048
    sgemm<2, false><<<dim3(16, 8, 16), 256, 0, st>>>(
        w.qkv + 512, w.qkv, w.sc, nullptr, nullptr, 64, 1, 8, 1536, 1536, 1024,
        1024LL * 1536, 64, 1024LL * 1536, 64, 8 * M1, M1, 0);
    // softmax over q
    {
        dim3 g(cB * cH * cS), blk(256);
        if (causal) softmax_kernel<true><<<g, blk, 0, st>>>(w.sc, padq, padk, 0.125f);
        else        softmax_kernel<false><<<g, blk, 0, st>>>(w.sc, padq, padk, 0.125f);
    }
    // PV (TA x NN, split-K=4): att[b*1024+q][h*64+j] = sum_k P[k][q]*V[k][j], grid 512
    sgemm<1, false><<<dim3(1, 8, 64), 256, 0, st>>>(
        w.sc, w.qkv + 1024, w.parts, nullptr, nullptr, 1024, 4, 8, 1024, 1536, 512,
        8 * M1, M1, 1024LL * 1536, 64, 1024LL * 512, 64, M1);
    reduce_flat<<<dim3(1024), 256, 0, st>>>(w.parts, w.att, M1, 4, M1, nullptr, 0, nullptr);
    // WO (NN, split-K=4): r = att @ WO + bO + resid, grid 512
    sgemm<0, false><<<dim3(8, 16, 4), 256, 0, st>>>(
        w.att, WO, w.parts, nullptr, nullptr, 512, 4, 1, 512, 512, 512,
        0, 0, 0, 0, 0, 0, M1);
    reduce_flat<<<dim3(1024), 256, 0, st>>>(w.parts, outR, M1, 4, M1, bO, 511, resid);
}

extern "C" void kernel_launch(void* const* d_in, const int* in_sizes, int n_in,
                              void* d_out, int out_size, void* d_ws, size_t ws_size,
                              hipStream_t stream)
{
    const float* X       = (const float*)d_in[0];
    const float* outp    = (const float*)d_in[1];
    const float* e_comb  = (const float*)d_in[2];
    const float* e_head  = (const float*)d_in[3];
    const float* e_WO    = (const float*)d_in[4];
    const float* e_bO    = (const float*)d_in[5];
    const float* e_W1    = (const float*)d_in[6];
    const float* e_W2    = (const float*)d_in[7];
    const float* ds_comb = (const float*)d_in[8];
    const float* ds_head = (const float*)d_in[9];
    const float* ds_WO   = (const float*)d_in[10];
    const float* ds_bO   = (const float*)d_in[11];
    const float* dc_comb = (const float*)d_in[12];
    const float* dc_head = (const float*)d_in[13];
    const float* dc_WO   = (const float*)d_in[14];
    const float* dc_bO   = (const float*)d_in[15];
    const float* d_W1    = (const float*)d_in[16];
    const float* d_W2    = (const float*)d_in[17];
    float* Y = (float*)d_out;

    Ws w;
    float* p = (float*)d_ws;
    const long long M1 = 1048576;
    w.t0   = p; p += M1;
    w.t1   = p; p += M1;
    w.t2   = p; p += M1;
    w.t3   = p; p += M1;
    w.wc3a = p; p += 6LL * 512 * 1536;      // 4,718,592
    w.qkv  = p; p += 2048LL * 1536;         // 3,145,728
    w.att  = p; p += M1;
    w.parts= p; p += 4 * M1;                // split-K compact planes (max 4M floats)
    w.sc   = p; p += 16LL * M1;             // 64 MB scores
    w.ffn  = w.sc;                          // [2048][2048] overlays sc
    w.pin  = (unsigned char*)p;
    w.pout = w.pin + cB * cS;

    // ---- prep ----
    pad_in_kernel <<<dim3(cB * cS), 256, 0, stream>>>(X, w.pin);
    pad_dec_kernel<<<dim3(cB * cS), 256, 0, stream>>>(outp, w.pout);
    posenc_enc_kernel<<<dim3(cB * cS), 256, 0, stream>>>(X, w.t0);
    posenc_dec_kernel<<<dim3(cB * cS), 256, 0, stream>>>(outp, w.t3);
    // all six Wc3 = comb @ head, one dispatch (order: enc0,enc1, ds0,ds1, dc0,dc1)
    wct_kernel<<<dim3(24, 4, 6), 256, 0, stream>>>(e_comb, e_head, ds_comb, ds_head, dc_comb, dc_head, w.wc3a);

    const dim3 lnGrid(cS * cD / 1024);

    // ---- encoder ----
    for (int i = 0; i < 2; ++i) {
        ln_kernel<<<lnGrid, 256, 0, stream>>>(w.t0, w.t1);
        run_mha(stream, w, i, w.t1, w.t1,
                e_WO + (long long)i * cD * cD, e_bO + i * cD,
                w.pin, w.pin, false, w.t1, w.t2);
        ln_kernel<<<lnGrid, 256, 0, stream>>>(w.t2, w.t1);
        sgemm<0, true><<<dim3(32, 16, 1), 256, 0, stream>>>(
            w.t1, e_W1 + (long long)i * cD * cDFF, w.ffn, nullptr, nullptr,
            512, 1, 1, 512, 2048, 2048, 0, 0, 0, 0, 0, 0, 0);
        sgemm<0, false><<<dim3(8, 16, 4), 256, 0, stream>>>(
            w.ffn, e_W2 + (long long)i * cDFF * cD, w.parts, nullptr, nullptr,
            2048, 4, 1, 2048, 512, 512, 0, 0, 0, 0, 0, 0, M1);
        reduce_flat<<<dim3(1024), 256, 0, stream>>>(w.parts, w.t0, M1, 4, M1, nullptr, 0, w.t1);
    }
    // w.t0 = enc_repr

    // ---- decoder ----
    for (int i = 0; i < 2; ++i) {
        ln_kernel<<<lnGrid, 256, 0, stream>>>(w.t3, w.t1);
        run_mha(stream, w, 2 + i, w.t1, w.t1,
                ds_WO + (long long)i * cD * cD, ds_bO + i * cD,
                w.pin, w.pin, /*causal=*/true, w.t1, w.t2);     // pad_in both (preserved bug)
        ln_kernel<<<lnGrid, 256, 0, stream>>>(w.t2, w.t1);
        run_mha(stream, w, 4 + i, w.t1, w.t0,
                dc_WO + (long long)i * cD * cD, dc_bO + i * cD,
                w.pout, w.pin, /*causal=*/false, w.t1, w.t2);
        ln_kernel<<<lnGrid, 256, 0, stream>>>(w.t2, w.t1);
        sgemm<0, true><<<dim3(32, 16, 1), 256, 0, stream>>>(
            w.t1, d_W1 + (long long)i * cD * cDFF, w.ffn, nullptr, nullptr,
            512, 1, 1, 512, 2048, 2048, 0, 0, 0, 0, 0, 0, 0);
        sgemm<0, false><<<dim3(8, 16, 4), 256, 0, stream>>>(
            w.ffn, d_W2 + (long long)i * cDFF * cD, w.parts, nullptr, nullptr,
            2048, 4, 1, 2048, 512, 512, 0, 0, 0, 0, 0, 0, M1);
        reduce_flat<<<dim3(1024), 256, 0, stream>>>(w.parts, w.t3, M1, 4, M1, nullptr, 0, w.t1);
    }

    final_kernel<<<dim3(cB * (cS - 1)), 256, 0, stream>>>(w.t3, w.pout, Y);
}

// Round 6
// 1872.696 us; speedup vs baseline: 1.7418x; 1.0570x over previous
//
#include <hip/hip_runtime.h>
#include <cstdint>
#include <cstddef>

// Problem constants (fixed by the reference)
constexpr int cB = 2, cS = 1024, cD = 512, cH = 8, cDK = 64, cDFF = 2048;
constexpr int cBS = cB * cS;
constexpr float kNEG = -1e19f;

// NUMERICS RULE (learned R5): the batch-dim layer_norm is a ±0.707 step around
// diff=0; changing any GEMM's fp32 accumulation order flips near-zero diffs and
// cascades O(1) errors to the output. Every GEMM below keeps a single fmaf
// chain with k strictly ascending, matching the R4-verified bit pattern.
// Split-K groupings are frozen at R4's (PV=4, WO=4, FFN2=4, crossQ=4, crossKV=2).

__device__ __forceinline__ float gelu_f(float x)
{
    return 0.5f * x * (1.0f + erff(x * 0.70710678118654752440f));
}

// ============================ SGEMM (fp32 vector) ============================
// Tile BM=128 x BN(64|128), BK=16, 256 threads, 8x(BN/16) microtile.
// BN=128 uses split columns {n0+tx*4, n0+64+tx*4} -> 2-addr/bank LDS reads (free).
// MODE: 0 = NN (A[m][k], B[k][n]); 1 = TA (A[k][m], B[k][n]); 2 = TB (A[m][k], B[n][k]).
// z = ((g1*G2+g2)*KS + kc); split-K (KS>1) writes plane kc at C + kc*plane.
// bias/resid only when KS==1.
template<int BN, int MODE, bool GELU>
__global__ __launch_bounds__(256) void sgemm(
    const float* __restrict__ A, const float* __restrict__ B, float* __restrict__ C,
    const float* __restrict__ bias, const float* __restrict__ resid,
    int K, int KS, int G2, int lda, int ldb, int ldc,
    long long a1, long long a2, long long b1, long long b2,
    long long c1, long long c2, long long plane)
{
    constexpr int BM = 128, BK = 16;
    constexpr int AP = BM + 4, BP = BN + 4;
    constexpr int MN = BN / 16;                      // 4 or 8 cols per thread
    __shared__ float As[BK][AP];
    __shared__ float Bs[BK][BP];

    const int z = blockIdx.z;
    const int kc = z % KS;
    const int zz = z / KS;
    const int g1 = zz / G2, g2 = zz % G2;
    const float* Ab = A + (long long)g1 * a1 + (long long)g2 * a2;
    const float* Bb = B + (long long)g1 * b1 + (long long)g2 * b2;
    float* Cb = C + (long long)g1 * c1 + (long long)g2 * c2 + (long long)kc * plane;
    const int klen = K / KS, kbase = kc * klen;
    const int m0 = blockIdx.y * BM, n0 = blockIdx.x * BN;
    const int t = threadIdx.x, tx = t & 15, ty = t >> 4;

    float acc[8][MN];
    #pragma unroll
    for (int i = 0; i < 8; ++i)
        #pragma unroll
        for (int j = 0; j < MN; ++j) acc[i][j] = 0.f;

    for (int k0 = kbase; k0 < kbase + klen; k0 += BK) {
        // ---- stage A (128x16 = 2 float4/thread) ----
        if (MODE == 1) {                              // TA: A stored [K][M]
            #pragma unroll
            for (int r = 0; r < 2; ++r) {
                const int c = r * 256 + t, kk = c >> 5, m4 = c & 31;
                *(float4*)&As[kk][m4 * 4] =
                    *(const float4*)&Ab[(long long)(k0 + kk) * lda + m0 + m4 * 4];
            }
        } else {                                      // A stored [M][K]
            #pragma unroll
            for (int r = 0; r < 2; ++r) {
                const int c = r * 256 + t, kq = c & 3, mm = c >> 2;
                float4 v = *(const float4*)&Ab[(long long)(m0 + mm) * lda + k0 + kq * 4];
                As[kq * 4 + 0][mm] = v.x; As[kq * 4 + 1][mm] = v.y;
                As[kq * 4 + 2][mm] = v.z; As[kq * 4 + 3][mm] = v.w;
            }
        }
        // ---- stage B (BNx16 = BN/64 float4/thread) ----
        if (MODE == 2) {                              // TB: B stored [N][K]
            #pragma unroll
            for (int r = 0; r < BN / 64; ++r) {
                const int c = r * 256 + t, kq = c & 3, nn = c >> 2;
                float4 v = *(const float4*)&Bb[(long long)(n0 + nn) * ldb + k0 + kq * 4];
                Bs[kq * 4 + 0][nn] = v.x; Bs[kq * 4 + 1][nn] = v.y;
                Bs[kq * 4 + 2][nn] = v.z; Bs[kq * 4 + 3][nn] = v.w;
            }
        } else {                                      // B stored [K][N]
            #pragma unroll
            for (int r = 0; r < BN / 64; ++r) {
                const int c = r * 256 + t, n4 = c & (BN / 4 - 1), kk = c / (BN / 4);
                *(float4*)&Bs[kk][n4 * 4] =
                    *(const float4*)&Bb[(long long)(k0 + kk) * ldb + n0 + n4 * 4];
            }
        }
        __syncthreads();
        #pragma unroll
        for (int kk = 0; kk < BK; ++kk) {
            float a[8], b[MN];
            *(float4*)&a[0] = *(const float4*)&As[kk][ty * 8];       // 4-addr broadcast/wave: free
            *(float4*)&a[4] = *(const float4*)&As[kk][ty * 8 + 4];
            *(float4*)&b[0] = *(const float4*)&Bs[kk][tx * 4];       // 2-addr/bank: free
            if (MN == 8)
                *(float4*)&b[4] = *(const float4*)&Bs[kk][64 + tx * 4];
            #pragma unroll
            for (int i = 0; i < 8; ++i)
                #pragma unroll
                for (int j = 0; j < MN; ++j)
                    acc[i][j] = fmaf(a[i], b[j], acc[i][j]);
        }
        __syncthreads();
    }

    // ---- epilogue ----
    #pragma unroll
    for (int i = 0; i < 8; ++i) {
        const int row = m0 + ty * 8 + i;
        #pragma unroll
        for (int g = 0; g < MN / 4; ++g) {
            const int col = n0 + g * 64 + tx * 4;
            float4 v;
            v.x = acc[i][g * 4 + 0]; v.y = acc[i][g * 4 + 1];
            v.z = acc[i][g * 4 + 2]; v.w = acc[i][g * 4 + 3];
            if (bias) {
                v.x += bias[col + 0]; v.y += bias[col + 1];
                v.z += bias[col + 2]; v.w += bias[col + 3];
            }
            if (GELU) {
                v.x = gelu_f(v.x); v.y = gelu_f(v.y);
                v.z = gelu_f(v.z); v.w = gelu_f(v.w);
            }
            const long long idx = (long long)row * ldc + col;
            if (resid) {
                float4 rr = *(const float4*)&resid[idx];
                v.x += rr.x; v.y += rr.y; v.z += rr.z; v.w += rr.w;
            }
            *(float4*)&Cb[idx] = v;
        }
    }
}

// ============================ split-K reduces ============================
// flat: out[i] = sum_z parts[z*plane+i] (+bias[i&ldcMask]) (+resid[i])
template<bool GELU>
__global__ __launch_bounds__(256) void reduce_flat(
    const float* __restrict__ parts, float* __restrict__ out, long long n,
    int ks, long long plane, const float* __restrict__ bias, int ldcMask,
    const float* __restrict__ resid)
{
    const long long i = ((long long)blockIdx.x * 256 + threadIdx.x) * 4;
    if (i >= n) return;
    float4 s = {0.f, 0.f, 0.f, 0.f};
    for (int z = 0; z < ks; ++z) {
        float4 v = *(const float4*)&parts[(long long)z * plane + i];
        s.x += v.x; s.y += v.y; s.z += v.z; s.w += v.w;
    }
    if (bias) {
        const int col = (int)(i & ldcMask);
        s.x += bias[col + 0]; s.y += bias[col + 1];
        s.z += bias[col + 2]; s.w += bias[col + 3];
    }
    if (GELU) {
        s.x = gelu_f(s.x); s.y = gelu_f(s.y);
        s.z = gelu_f(s.z); s.w = gelu_f(s.w);
    }
    if (resid) {
        float4 rr = *(const float4*)&resid[i];
        s.x += rr.x; s.y += rr.y; s.z += rr.z; s.w += rr.w;
    }
    *(float4*)&out[i] = s;
}

// scatter: compact [M][N](pow2 N) planes -> out[row*ldcOut + colBase + col]
__global__ __launch_bounds__(256) void reduce_scatter(
    const float* __restrict__ parts, float* __restrict__ out, long long n,
    int ks, long long plane, int logN, int maskN, int ldcOut, int colBase)
{
    const long long i = ((long long)blockIdx.x * 256 + threadIdx.x) * 4;
    if (i >= n) return;
    float4 s = {0.f, 0.f, 0.f, 0.f};
    for (int z = 0; z < ks; ++z) {
        float4 v = *(const float4*)&parts[(long long)z * plane + i];
        s.x += v.x; s.y += v.y; s.z += v.z; s.w += v.w;
    }
    const long long row = i >> logN;
    const int col = (int)(i & maskN);
    *(float4*)&out[row * ldcOut + colBase + col] = s;
}

// ============================ Wc3 (tiled GEMM, all 6 MHAs, one dispatch) ============
// block bid: mt = bid&3 (m-tile of 128 rows), zp = bid>>2 -> (zi, p, h).
// C[zi][512][1536] cols p*512+h*64..+63. A = comb[p] (512x64), B = head[p][h] (64x64).
// k-accumulation: single fmaf chain, k ascending 0..63 — bit-identical to R4's wct.
__global__ __launch_bounds__(256) void wct_gemm(
    const float* __restrict__ ec, const float* __restrict__ eh,
    const float* __restrict__ dsc, const float* __restrict__ dsh,
    const float* __restrict__ dcc, const float* __restrict__ dch,
    float* __restrict__ Wc3)
{
    constexpr long long LWH = 3LL * 512 * 64;          // per-layer comb/head stride
    __shared__ float As[16][132];
    __shared__ float Bs[16][68];
    const int bid = blockIdx.x;
    const int mt = bid & 3;
    const int zp = bid >> 2;                           // 0..143
    const int zi = zp / 24;
    const int ph = zp % 24;
    const int p = ph >> 3, h = ph & 7;
    const int l = zi & 1;
    const float* comb = (zi < 2) ? ec : (zi < 4) ? dsc : dcc;
    const float* head = (zi < 2) ? eh : (zi < 4) ? dsh : dch;
    const float* Ab = comb + l * LWH + (long long)p * 512 * 64 + mt * 128 * 64;
    const float* Bb = head + l * LWH + (long long)ph * 4096;
    float* Cb = Wc3 + (long long)zi * 512 * 1536 + (long long)mt * 128 * 1536 + p * 512 + h * 64;
    const int t = threadIdx.x, tx = t & 15, ty = t >> 4;

    float acc[8][4];
    #pragma unroll
    for (int i = 0; i < 8; ++i)
        #pragma unroll
        for (int j = 0; j < 4; ++j) acc[i][j] = 0.f;

    for (int k0 = 0; k0 < 64; k0 += 16) {
        #pragma unroll
        for (int r = 0; r < 2; ++r) {
            const int c = r * 256 + t, kq = c & 3, mm = c >> 2;
            float4 v = *(const float4*)&Ab[mm * 64 + k0 + kq * 4];
            As[kq * 4 + 0][mm] = v.x; As[kq * 4 + 1][mm] = v.y;
            As[kq * 4 + 2][mm] = v.z; As[kq * 4 + 3][mm] = v.w;
        }
        {
            const int n4 = t & 15, kk = t >> 4;
            *(float4*)&Bs[kk][n4 * 4] = *(const float4*)&Bb[(k0 + kk) * 64 + n4 * 4];
        }
        __syncthreads();
        #pragma unroll
        for (int kk = 0; kk < 16; ++kk) {
            float a[8];
            *(float4*)&a[0] = *(const float4*)&As[kk][ty * 8];
            *(float4*)&a[4] = *(const float4*)&As[kk][ty * 8 + 4];
            float4 b4 = *(const float4*)&Bs[kk][tx * 4];
            const float b[4] = {b4.x, b4.y, b4.z, b4.w};
            #pragma unroll
            for (int i = 0; i < 8; ++i)
                #pragma unroll
                for (int j = 0; j < 4; ++j)
                    acc[i][j] = fmaf(a[i], b[j], acc[i][j]);
        }
        __syncthreads();
    }
    #pragma unroll
    for (int i = 0; i < 8; ++i) {
        const int row = ty * 8 + i;
        float4 v;
        v.x = acc[i][0]; v.y = acc[i][1]; v.z = acc[i][2]; v.w = acc[i][3];
        *(float4*)&Cb[(long long)row * 1536 + tx * 4] = v;
    }
}

// ============================ softmax over QUERY dim ============================
template<bool CAUSAL>
__global__ __launch_bounds__(256) void softmax_kernel(
    float* __restrict__ sc, const unsigned char* __restrict__ padq,
    const unsigned char* __restrict__ padk, float scale)
{
    const int r = blockIdx.x;             // (b*H + h)*S + k
    const int k = r & (cS - 1);
    const int b = r / (cH * cS);
    float* row = sc + (long long)r * cS;
    const bool pk = padk[b * cS + k] != 0;
    const int tid = threadIdx.x;
    float4 v4 = reinterpret_cast<const float4*>(row)[tid];
    float vals[4] = {v4.x, v4.y, v4.z, v4.w};
    #pragma unroll
    for (int u = 0; u < 4; ++u) {
        const int q = tid * 4 + u;
        bool masked = pk || (padq[b * cS + q] != 0);
        if (CAUSAL) masked = masked || (q < k);
        float x = vals[u];
        if (masked) x += kNEG;
        if (!CAUSAL) x *= scale;
        vals[u] = x;
    }
    float m = fmaxf(fmaxf(vals[0], vals[1]), fmaxf(vals[2], vals[3]));
    #pragma unroll
    for (int off = 32; off > 0; off >>= 1) m = fmaxf(m, __shfl_down(m, off));
    __shared__ float red[8];
    if ((tid & 63) == 0) red[tid >> 6] = m;
    __syncthreads();
    const float rm = fmaxf(fmaxf(red[0], red[1]), fmaxf(red[2], red[3]));
    float e[4], s = 0.f;
    #pragma unroll
    for (int u = 0; u < 4; ++u) { e[u] = expf(vals[u] - rm); s += e[u]; }
    #pragma unroll
    for (int off = 32; off > 0; off >>= 1) s += __shfl_down(s, off);
    if ((tid & 63) == 0) red[4 + (tid >> 6)] = s;
    __syncthreads();
    float inv = 1.0f / (red[4] + red[5] + red[6] + red[7]);
    if (CAUSAL) inv *= scale;
    v4.x = e[0] * inv; v4.y = e[1] * inv; v4.z = e[2] * inv; v4.w = e[3] * inv;
    reinterpret_cast<float4*>(row)[tid] = v4;
}

// ============================ batch-dim layer norm (B=2 closed form) ============================
__global__ __launch_bounds__(256) void ln_kernel(const float* __restrict__ x, float* __restrict__ out)
{
    const long long idx = ((long long)blockIdx.x * 256 + threadIdx.x) * 4;
    float4 x0 = *(const float4*)&x[idx];
    float4 x1 = *(const float4*)&x[idx + (long long)cS * cD];
    float4 o;
    {
        const float d0 = x0.x - x1.x; o.x = (0.5f * d0) / (fabsf(d0) * 0.70710678f + 1e-4f);
        const float d1 = x0.y - x1.y; o.y = (0.5f * d1) / (fabsf(d1) * 0.70710678f + 1e-4f);
        const float d2 = x0.z - x1.z; o.z = (0.5f * d2) / (fabsf(d2) * 0.70710678f + 1e-4f);
        const float d3 = x0.w - x1.w; o.w = (0.5f * d3) / (fabsf(d3) * 0.70710678f + 1e-4f);
    }
    *(float4*)&out[idx] = o;
    float4 n;
    n.x = -o.x; n.y = -o.y; n.z = -o.z; n.w = -o.w;
    *(float4*)&out[idx + (long long)cS * cD] = n;
}

// ============================ padding masks ============================
__global__ __launch_bounds__(256) void pad_in_kernel(const float* __restrict__ X, unsigned char* __restrict__ pad)
{
    const int r = blockIdx.x;
    const float* row = X + (long long)r * cD;
    const int tid = threadIdx.x;
    const bool nz = (row[tid] != 0.f) | (row[tid + 256] != 0.f);
    unsigned long long w = __ballot(nz);
    __shared__ unsigned long long sh[4];
    if ((tid & 63) == 0) sh[tid >> 6] = w;
    __syncthreads();
    if (tid == 0) pad[r] = ((sh[0] | sh[1] | sh[2] | sh[3]) == 0ULL) ? 1 : 0;
}

__global__ __launch_bounds__(256) void pad_dec_kernel(const float* __restrict__ outp, unsigned char* __restrict__ pad)
{
    const int r = blockIdx.x;
    const int s = r & (cS - 1);
    const int b = r >> 10;
    if (s == 0) { if (threadIdx.x == 0) pad[r] = 0; return; }
    const float* row = outp + ((long long)b * (cS - 1) + (s - 1)) * cD;
    const int tid = threadIdx.x;
    const bool nz = (row[tid] != 0.f) | (row[tid + 256] != 0.f);
    unsigned long long w = __ballot(nz);
    __shared__ unsigned long long sh[4];
    if ((tid & 63) == 0) sh[tid >> 6] = w;
    __syncthreads();
    if (tid == 0) pad[r] = ((sh[0] | sh[1] | sh[2] | sh[3]) == 0ULL) ? 1 : 0;
}

// ============================ positional encoding ============================
__device__ __forceinline__ float pe_val(int s, int d)
{
    const int i2 = d & ~1;
    const float dv = powf(10000.0f, -(float)i2 / (float)cD);
    const float ang = (float)s * dv;
    return (d & 1) ? cosf(ang) : sinf(ang);
}

__global__ __launch_bounds__(256) void posenc_enc_kernel(const float* __restrict__ X, float* __restrict__ out)
{
    const int r = blockIdx.x;
    const int s = r & (cS - 1);
    const int tid = threadIdx.x;
    #pragma unroll
    for (int u = 0; u < 2; ++u) {
        const int d = tid + 256 * u;
        out[(long long)r * cD + d] = X[(long long)r * cD + d] + pe_val(s, d);
    }
}

__global__ __launch_bounds__(256) void posenc_dec_kernel(const float* __restrict__ outp, float* __restrict__ out)
{
    const int r = blockIdx.x;
    const int s = r & (cS - 1);
    const int b = r >> 10;
    const int tid = threadIdx.x;
    #pragma unroll
    for (int u = 0; u < 2; ++u) {
        const int d = tid + 256 * u;
        const float base = (s == 0) ? 1.0f : outp[((long long)b * (cS - 1) + (s - 1)) * cD + d];
        out[(long long)r * cD + d] = base + pe_val(s, d);
    }
}

// ============================ final masked slice ============================
__global__ __launch_bounds__(256) void final_kernel(const float* __restrict__ cur,
                                                    const unsigned char* __restrict__ pad,
                                                    float* __restrict__ out)
{
    const int r = blockIdx.x;
    const int b = r / (cS - 1);
    const int s = r - b * (cS - 1) + 1;
    const int tid = threadIdx.x;
    const bool p = pad[b * cS + s] != 0;
    #pragma unroll
    for (int u = 0; u < 2; ++u) {
        const int d = tid + 256 * u;
        out[(long long)r * cD + d] = p ? 0.0f : cur[((long long)b * cS + s) * cD + d];
    }
}

// ============================ host orchestration ============================
struct Ws {
    float *t0, *t1, *t2, *t3, *wc3a, *qkv, *att, *parts, *sc, *ffn;
    unsigned char *pin, *pout;
};

static void run_mha(hipStream_t st, const Ws& w, int mhaIdx,
                    const float* xq, const float* xkv,
                    const float* WO, const float* bO,
                    const unsigned char* padq, const unsigned char* padk,
                    bool causal, const float* resid, float* outR)
{
    const long long M1 = 1048576;
    const float* wc3 = w.wc3a + (long long)mhaIdx * 512 * 1536;
    if (xq == xkv) {
        // fused QKV (NN, BN=64, KS=1, grid 384) — R4 bit-exact
        sgemm<64, 0, false><<<dim3(24, 16, 1), 256, 0, st>>>(
            xq, wc3, w.qkv, nullptr, nullptr, 512, 1, 1, 512, 1536, 1536,
            0, 0, 0, 0, 0, 0, 0);
    } else {
        // cross: Q (split-K=4), K/V (split-K=2) — R4 bit-exact
        sgemm<64, 0, false><<<dim3(8, 16, 4), 256, 0, st>>>(
            xq, wc3, w.parts, nullptr, nullptr, 512, 4, 1, 512, 1536, 512,
            0, 0, 0, 0, 0, 0, M1);
        reduce_scatter<<<dim3(1024), 256, 0, st>>>(w.parts, w.qkv, M1, 4, M1, 9, 511, 1536, 0);
        sgemm<64, 0, false><<<dim3(16, 16, 2), 256, 0, st>>>(
            xkv, wc3 + 512, w.parts, nullptr, nullptr, 512, 2, 1, 512, 1536, 1024,
            0, 0, 0, 0, 0, 0, 2 * M1);
        reduce_scatter<<<dim3(2048), 256, 0, st>>>(w.parts, w.qkv, 2 * M1, 2, 2 * M1, 10, 1023, 1536, 512);
    }
    // scoresT[b,h][k][q] = K . Q (TB, BN=128, grid 1024) — order-preserving (serial k=0..63)
    sgemm<128, 2, false><<<dim3(8, 8, 16), 256, 0, st>>>(
        w.qkv + 512, w.qkv, w.sc, nullptr, nullptr, 64, 1, 8, 1536, 1536, 1024,
        1024LL * 1536, 64, 1024LL * 1536, 64, 8 * M1, M1, 0);
    // softmax over q
    {
        dim3 g(cB * cH * cS), blk(256);
        if (causal) softmax_kernel<true><<<g, blk, 0, st>>>(w.sc, padq, padk, 0.125f);
        else        softmax_kernel<false><<<g, blk, 0, st>>>(w.sc, padq, padk, 0.125f);
    }
    // PV (TA x NN, BN=64, split-K=4, grid 512) — R4 bit-exact
    sgemm<64, 1, false><<<dim3(1, 8, 64), 256, 0, st>>>(
        w.sc, w.qkv + 1024, w.parts, nullptr, nullptr, 1024, 4, 8, 1024, 1536, 512,
        8 * M1, M1, 1024LL * 1536, 64, 1024LL * 512, 64, M1);
    reduce_flat<false><<<dim3(1024), 256, 0, st>>>(w.parts, w.att, M1, 4, M1, nullptr, 0, nullptr);
    // WO (NN, BN=64, split-K=4, grid 512) — R4 bit-exact
    sgemm<64, 0, false><<<dim3(8, 16, 4), 256, 0, st>>>(
        w.att, WO, w.parts, nullptr, nullptr, 512, 4, 1, 512, 512, 512,
        0, 0, 0, 0, 0, 0, M1);
    reduce_flat<false><<<dim3(1024), 256, 0, st>>>(w.parts, outR, M1, 4, M1, bO, 511, resid);
}

extern "C" void kernel_launch(void* const* d_in, const int* in_sizes, int n_in,
                              void* d_out, int out_size, void* d_ws, size_t ws_size,
                              hipStream_t stream)
{
    const float* X       = (const float*)d_in[0];
    const float* outp    = (const float*)d_in[1];
    const float* e_comb  = (const float*)d_in[2];
    const float* e_head  = (const float*)d_in[3];
    const float* e_WO    = (const float*)d_in[4];
    const float* e_bO    = (const float*)d_in[5];
    const float* e_W1    = (const float*)d_in[6];
    const float* e_W2    = (const float*)d_in[7];
    const float* ds_comb = (const float*)d_in[8];
    const float* ds_head = (const float*)d_in[9];
    const float* ds_WO   = (const float*)d_in[10];
    const float* ds_bO   = (const float*)d_in[11];
    const float* dc_comb = (const float*)d_in[12];
    const float* dc_head = (const float*)d_in[13];
    const float* dc_WO   = (const float*)d_in[14];
    const float* dc_bO   = (const float*)d_in[15];
    const float* d_W1    = (const float*)d_in[16];
    const float* d_W2    = (const float*)d_in[17];
    float* Y = (float*)d_out;

    Ws w;
    float* p = (float*)d_ws;
    const long long M1 = 1048576;
    w.t0   = p; p += M1;
    w.t1   = p; p += M1;
    w.t2   = p; p += M1;
    w.t3   = p; p += M1;
    w.wc3a = p; p += 6LL * 512 * 1536;      // 4,718,592
    w.qkv  = p; p += 2048LL * 1536;         // 3,145,728
    w.att  = p; p += M1;
    w.parts= p; p += 4 * M1;                // split-K compact planes (PV/WO/FFN2/cross)
    w.sc   = p; p += 16LL * M1;             // 64 MB scores
    w.ffn  = w.sc;                          // [2048][2048] overlays sc[0..4M1]
    w.pin  = (unsigned char*)p;
    w.pout = w.pin + cB * cS;

    // ---- prep ----
    pad_in_kernel <<<dim3(cB * cS), 256, 0, stream>>>(X, w.pin);
    pad_dec_kernel<<<dim3(cB * cS), 256, 0, stream>>>(outp, w.pout);
    posenc_enc_kernel<<<dim3(cB * cS), 256, 0, stream>>>(X, w.t0);
    posenc_dec_kernel<<<dim3(cB * cS), 256, 0, stream>>>(outp, w.t3);
    // all six Wc3 = comb @ head, tiled GEMM, one dispatch (enc0,enc1, ds0,ds1, dc0,dc1)
    wct_gemm<<<dim3(576), 256, 0, stream>>>(e_comb, e_head, ds_comb, ds_head, dc_comb, dc_head, w.wc3a);

    const dim3 lnGrid(cS * cD / 1024);

    // ---- encoder ----
    for (int i = 0; i < 2; ++i) {
        ln_kernel<<<lnGrid, 256, 0, stream>>>(w.t0, w.t1);
        run_mha(stream, w, i, w.t1, w.t1,
                e_WO + (long long)i * cD * cD, e_bO + i * cD,
                w.pin, w.pin, false, w.t1, w.t2);
        ln_kernel<<<lnGrid, 256, 0, stream>>>(w.t2, w.t1);
        // FFN1 (BN=64, KS=1, grid 512, GELU in epilogue) — R4 bit-exact
        sgemm<64, 0, true><<<dim3(32, 16, 1), 256, 0, stream>>>(
            w.t1, e_W1 + (long long)i * cD * cDFF, w.ffn, nullptr, nullptr,
            512, 1, 1, 512, 2048, 2048, 0, 0, 0, 0, 0, 0, 0);
        // FFN2 (BN=64, split-K=4, grid 512) — R4 bit-exact
        sgemm<64, 0, false><<<dim3(8, 16, 4), 256, 0, stream>>>(
            w.ffn, e_W2 + (long long)i * cDFF * cD, w.parts, nullptr, nullptr,
            2048, 4, 1, 2048, 512, 512, 0, 0, 0, 0, 0, 0, M1);
        reduce_flat<false><<<dim3(1024), 256, 0, stream>>>(w.parts, w.t0, M1, 4, M1, nullptr, 0, w.t1);
    }
    // w.t0 = enc_repr

    // ---- decoder ----
    for (int i = 0; i < 2; ++i) {
        ln_kernel<<<lnGrid, 256, 0, stream>>>(w.t3, w.t1);
        run_mha(stream, w, 2 + i, w.t1, w.t1,
                ds_WO + (long long)i * cD * cD, ds_bO + i * cD,
                w.pin, w.pin, /*causal=*/true, w.t1, w.t2);     // pad_in both (preserved bug)
        ln_kernel<<<lnGrid, 256, 0, stream>>>(w.t2, w.t1);
        run_mha(stream, w, 4 + i, w.t1, w.t0,
                dc_WO + (long long)i * cD * cD, dc_bO + i * cD,
                w.pout, w.pin, /*causal=*/false, w.t1, w.t2);
        ln_kernel<<<lnGrid, 256, 0, stream>>>(w.t2, w.t1);
        sgemm<64, 0, true><<<dim3(32, 16, 1), 256, 0, stream>>>(
            w.t1, d_W1 + (long long)i * cD * cDFF, w.ffn, nullptr, nullptr,
            512, 1, 1, 512, 2048, 2048, 0, 0, 0, 0, 0, 0, 0);
        sgemm<64, 0, false><<<dim3(8, 16, 4), 256, 0, stream>>>(
            w.ffn, d_W2 + (long long)i * cDFF * cD, w.parts, nullptr, nullptr,
            2048, 4, 1, 2048, 512, 512, 0, 0, 0, 0, 0, 0, M1);
        reduce_flat<false><<<dim3(1024), 256, 0, stream>>>(w.parts, w.t3, M1, 4, M1, nullptr, 0, w.t1);
    }

    final_kernel<<<dim3(cB * (cS - 1)), 256, 0, stream>>>(w.t3, w.pout, Y);
}